// Round 8
// baseline (327.130 us; speedup 1.0000x reference)
//
#include <hip/hip_runtime.h>

// ArcFace loss, MI355X. B=512, D=512, C=64000, s=64, m=0.5.
// R15 = producer/consumer wave specialization (AITER pattern).
// R14 post-mortem: spill gone (WRITE 16MB) but VGPR squeezed to 64 by
// launch_bounds(256,4) -> compiler serialized the A-prefetch -> every
// k-step eats full L2/L3 latency -> MfmaUtil 12%, gemm 113us.
// R15: block = 640 thr. Waves 0..7 = consumers running R7's PROVEN
// no-spill K-loop (acc4x4, af/afn prefetch) on sW[cur]; waves 8,9 =
// producers streaming tile t+1's 64 W rows (nt fp32) -> bf16 pack ->
// swizzled ds_write into sW[cur^1] + ||w||^2 -> norms2[cur^1].
// W-stream vmcnt lives in producer waves only -> no coupling with the
// consumer A-prefetch. One uniform barrier per tile. 128KB LDS dbuf ->
// 1 block/CU; launch_bounds(640,2) -> VGPR cap 256 (no squeeze).
// Grid 250 persistent x 4 tiles of 64 classes; W read exactly once.
// Keeps postponed normalization (theta = dot(x_hat,bf16(w)) / ||w||).

#define B_N 512
#define D_N 512
#define C_N 64000
#define S_SCALE 64.0f
#define MARGIN 0.5f
#define EPS_C 1e-7f
#define NREP 16
#define TPB 4            // 64-class tiles per block
#define GRID_GEMM 250    // 250 * 4 * 64 = 64000 classes
#define NCONS 8          // consumer waves
#define NTHREADS 640     // 8 consumer + 2 producer waves

typedef unsigned short ushort_t;
typedef __attribute__((ext_vector_type(8))) short short8;   // 8 bf16 (4 VGPRs)
typedef __attribute__((ext_vector_type(4))) float floatx4;  // MFMA acc
typedef __attribute__((ext_vector_type(4))) float fvec4;    // nt loads

__device__ __forceinline__ ushort_t f2bf(float f) {
    unsigned int u = __float_as_uint(f);
    u += 0x7fffu + ((u >> 16) & 1u);  // round-to-nearest-even
    return (ushort_t)(u >> 16);
}

// Normalize x rows -> bf16 in fragment-linear layout:
//   xnT element addr = (kc*512 + row)*8 + j,  kc = k/8 in [0,64), j = k%8.
// Blocks 0..127: 4 rows each. Block 128: zero rowsum replicas.
__global__ void xprep_kernel(const float* __restrict__ x,
                             ushort_t* __restrict__ xnT,
                             float* __restrict__ rowsumR) {
    int b = blockIdx.x;
    int t = threadIdx.x;
    if (b == 128) {
#pragma unroll
        for (int i = 0; i < NREP * B_N / 256; ++i)
            rowsumR[i * 256 + t] = 0.0f;
        return;
    }
    int row  = b * 4 + (t >> 6);
    int lane = t & 63;
    const float4* p = (const float4*)(x + (size_t)row * D_N);
    float4 v0 = p[lane * 2];        // elems [lane*8 .. lane*8+3]
    float4 v1 = p[lane * 2 + 1];    // elems [lane*8+4 .. lane*8+7]
    float ss = v0.x*v0.x + v0.y*v0.y + v0.z*v0.z + v0.w*v0.w
             + v1.x*v1.x + v1.y*v1.y + v1.z*v1.z + v1.w*v1.w;
#pragma unroll
    for (int off = 32; off > 0; off >>= 1) ss += __shfl_xor(ss, off);
    float sc = 1.0f / fmaxf(sqrtf(ss), 1e-12f);
    uint4 o;
    o.x = (unsigned)f2bf(v0.x*sc) | ((unsigned)f2bf(v0.y*sc) << 16);
    o.y = (unsigned)f2bf(v0.z*sc) | ((unsigned)f2bf(v0.w*sc) << 16);
    o.z = (unsigned)f2bf(v1.x*sc) | ((unsigned)f2bf(v1.y*sc) << 16);
    o.w = (unsigned)f2bf(v1.z*sc) | ((unsigned)f2bf(v1.w*sc) << 16);
    *((uint4*)(xnT + ((size_t)(lane << 9) + row) * 8)) = o;
}

// Persistent block: 4 tiles of (64 classes x 512 rows). Consumer wave w
// owns rows [w*64, w*64+64) x tile cols [0,64) as 4x4 16x16x32 frags.
// sW (XOR swizzle): ushort addr = kc*512 + (row^(kc&7))*8 + j; raw
// bf16(w). norms2[buf][row] = ||w||^2 fp32 (postponed normalization).
__global__ __launch_bounds__(NTHREADS, 2)
void gemm_fused_kernel(const float* __restrict__ W,
                       const ushort_t* __restrict__ xnT,
                       const int* __restrict__ y,
                       float* __restrict__ rowsumR,
                       float* __restrict__ tgt) {
    __shared__ ushort_t sW[2][64 * 512];   // 128 KB double-buffered B tile
    __shared__ float    norms2[2][64];     // per-class ||w||^2

    const int t    = threadIdx.x;
    const int lane = t & 63;
    const int w    = t >> 6;     // wave 0..9
    const int lq   = lane >> 4;  // quad
    const int lc   = lane & 15;
    const int cbase = blockIdx.x * (TPB * 64);
    const int rep   = blockIdx.x & (NREP - 1);

    // ---- prologue: consumer waves stage tile 0 (8 rows each) ----
    if (w < NCONS) {
#pragma unroll 4
        for (int rr = 0; rr < 8; ++rr) {
            int row = w * 8 + rr;  // 0..63
            const fvec4* p = (const fvec4*)(W + (size_t)(cbase + row) * D_N);
            fvec4 a = __builtin_nontemporal_load(p + lane * 2);
            fvec4 b = __builtin_nontemporal_load(p + lane * 2 + 1);
            float ss = a.x*a.x + a.y*a.y + a.z*a.z + a.w*a.w
                     + b.x*b.x + b.y*b.y + b.z*b.z + b.w*b.w;
#pragma unroll
            for (int off = 32; off > 0; off >>= 1) ss += __shfl_xor(ss, off);
            uint4 o;
            o.x = (unsigned)f2bf(a.x) | ((unsigned)f2bf(a.y) << 16);
            o.y = (unsigned)f2bf(a.z) | ((unsigned)f2bf(a.w) << 16);
            o.z = (unsigned)f2bf(b.x) | ((unsigned)f2bf(b.y) << 16);
            o.w = (unsigned)f2bf(b.z) | ((unsigned)f2bf(b.w) << 16);
            *((uint4*)(&sW[0][lane * 512 + (row ^ (lane & 7)) * 8])) = o;
            if (lane == 0) norms2[0][row] = ss;
        }
    }
    __syncthreads();

    int cur = 0;
#pragma unroll 1
    for (int tt = 0; tt < TPB; ++tt) {
        const int cn0 = cbase + tt * 64;
        const ushort_t* sWc = &sW[cur][0];
        const float*    n2c = &norms2[cur][0];

        if (w < NCONS) {
            // ================= CONSUMER: R7-verbatim K-loop =================
            const ushort_t* apT[4];
#pragma unroll
            for (int tm = 0; tm < 4; tm++)
                apT[tm] = xnT + ((size_t)lq * 512 + w * 64 + tm * 16 + lc) * 8;

            floatx4 acc[4][4];
#pragma unroll
            for (int i = 0; i < 4; i++)
#pragma unroll
                for (int j = 0; j < 4; j++)
                    acc[i][j] = (floatx4){0.f, 0.f, 0.f, 0.f};

            short8 af[4], afn[4];
#pragma unroll
            for (int tm = 0; tm < 4; tm++) af[tm] = *(const short8*)(apT[tm]);

            for (int k = 0; k < 16; ++k) {
                if (k < 15) {
#pragma unroll
                    for (int tm = 0; tm < 4; tm++)
                        afn[tm] = *(const short8*)(apT[tm] + (k + 1) * 16384);
                }
                int kc = k * 4 + lq;
                short8 bfr[4];
#pragma unroll
                for (int tn = 0; tn < 4; tn++) {
                    int rs = (tn * 16 + lc) ^ (kc & 7);
                    bfr[tn] = *(const short8*)(&sWc[kc * 512 + rs * 8]);
                }
#pragma unroll
                for (int tm = 0; tm < 4; tm++)
#pragma unroll
                    for (int tn = 0; tn < 4; tn++)
                        acc[tm][tn] = __builtin_amdgcn_mfma_f32_16x16x32_bf16(
                            af[tm], bfr[tn], acc[tm][tn], 0, 0, 0);
                if (k < 15) {
#pragma unroll
                    for (int tm = 0; tm < 4; tm++) af[tm] = afn[tm];
                }
            }

            // ---- epilogue: theta = acc * rsqrt(||w||^2) (postponed norm)
            float rn[4];
#pragma unroll
            for (int tn = 0; tn < 4; tn++)
                rn[tn] = 1.0f / fmaxf(sqrtf(n2c[tn * 16 + lc]), 1e-12f);
#pragma unroll
            for (int tm = 0; tm < 4; tm++) {
#pragma unroll
                for (int r = 0; r < 4; r++) {
                    int grow = w * 64 + tm * 16 + lq * 4 + r;  // 0..511
                    int yv   = y[grow];
                    float es = 0.0f;
#pragma unroll
                    for (int tn = 0; tn < 4; tn++) {
                        int gcol = cn0 + tn * 16 + lc;
                        float theta = acc[tm][tn][r] * rn[tn];
                        if (gcol == yv) {
                            tgt[grow] = theta;  // one writer device-wide
                        } else {
                            es += __expf(S_SCALE * theta);
                        }
                    }
                    // reduce across 16 lc lanes (lq groups stay distinct)
#pragma unroll
                    for (int off = 1; off < 16; off <<= 1)
                        es += __shfl_xor(es, off);
                    if (lc == 0)
                        atomicAdd(&rowsumR[rep * B_N + grow], es);
                }
            }
        } else if (tt < TPB - 1) {
            // ================= PRODUCER: stage tile tt+1 =================
            ushort_t* sWn = &sW[cur ^ 1][0];
            float*    n2n = &norms2[cur ^ 1][0];
            const int nb  = cn0 + 64;             // next tile class base
            const int r0  = (w - NCONS) * 32;     // rows 0..31 / 32..63
#pragma unroll 1
            for (int rb = 0; rb < 32; rb += 8) {
                fvec4 av[8], bv[8];
#pragma unroll
                for (int j = 0; j < 8; ++j) {
                    const fvec4* p =
                        (const fvec4*)(W + (size_t)(nb + r0 + rb + j) * D_N);
                    av[j] = __builtin_nontemporal_load(p + lane * 2);
                    bv[j] = __builtin_nontemporal_load(p + lane * 2 + 1);
                }
#pragma unroll
                for (int j = 0; j < 8; ++j) {
                    int row = r0 + rb + j;
                    fvec4 a = av[j];
                    fvec4 b = bv[j];
                    float ss = a.x*a.x + a.y*a.y + a.z*a.z + a.w*a.w
                             + b.x*b.x + b.y*b.y + b.z*b.z + b.w*b.w;
#pragma unroll
                    for (int off = 32; off > 0; off >>= 1)
                        ss += __shfl_xor(ss, off);
                    uint4 o;
                    o.x = (unsigned)f2bf(a.x) | ((unsigned)f2bf(a.y) << 16);
                    o.y = (unsigned)f2bf(a.z) | ((unsigned)f2bf(a.w) << 16);
                    o.z = (unsigned)f2bf(b.x) | ((unsigned)f2bf(b.y) << 16);
                    o.w = (unsigned)f2bf(b.z) | ((unsigned)f2bf(b.w) << 16);
                    *((uint4*)(&sWn[lane * 512 + (row ^ (lane & 7)) * 8])) = o;
                    if (lane == 0) n2n[row] = ss;
                }
            }
        }
        __syncthreads();  // tile tt done everywhere; tile tt+1 staged
        cur ^= 1;
    }
}

__global__ void finalize_kernel(const float* __restrict__ rowsumR,
                                const float* __restrict__ tgt,
                                float* __restrict__ out) {
    __shared__ float red[256];
    int t = threadIdx.x;
    float s = 0.0f;
    for (int r = t; r < B_N; r += 256) {
        float rs = 0.0f;
#pragma unroll
        for (int i = 0; i < NREP; ++i) rs += rowsumR[i * B_N + r];
        float tv = tgt[r];
        tv = fminf(fmaxf(tv, -1.0f + EPS_C), 1.0f - EPS_C);
        float num = S_SCALE * cosf(acosf(tv) + MARGIN);
        float den = expf(num) + rs;
        s += num - logf(den);
    }
    red[t] = s;
    __syncthreads();
    for (int o = 128; o > 0; o >>= 1) {
        if (t < o) red[t] += red[t + o];
        __syncthreads();
    }
    if (t == 0) out[0] = -red[0] / (float)B_N;
}

extern "C" void kernel_launch(void* const* d_in, const int* in_sizes, int n_in,
                              void* d_out, int out_size, void* d_ws, size_t ws_size,
                              hipStream_t stream) {
    const float* x = (const float*)d_in[0];
    const int*   y = (const int*)d_in[1];
    const float* W = (const float*)d_in[2];
    float* out = (float*)d_out;

    char* ws = (char*)d_ws;
    ushort_t* xnT   = (ushort_t*)ws;                    // 512 KB (frag-linear)
    float* rowsumR  = (float*)(ws + 524288);            // 32 KB (16 replicas)
    float* tgt      = rowsumR + NREP * B_N;             // 2 KB

    xprep_kernel<<<129, 256, 0, stream>>>(x, xnT, rowsumR);
    gemm_fused_kernel<<<GRID_GEMM, NTHREADS, 0, stream>>>(W, xnT, y, rowsumR, tgt);
    finalize_kernel<<<1, 256, 0, stream>>>(rowsumR, tgt, out);
}